// Round 4
// baseline (237.608 us; speedup 1.0000x reference)
//
#include <hip/hip_runtime.h>
#include <math.h>

#define L_ 4096
#define B_ 4
#define D_ 512
#define V_ 1000
#define VP 1024
#define BD 2048   // B_*D_
#define OUT_BV 4000  // B_*V_
#define NCH 8     // split-K chunks for kGbf

typedef __attribute__((ext_vector_type(8))) short short8;
typedef __attribute__((ext_vector_type(4))) float f32x4;
typedef __attribute__((ext_vector_type(4))) short short4v;

__device__ __forceinline__ short f2bf(float f) {
  unsigned u = __float_as_uint(f);
  unsigned r = (u + 0x7FFFu + ((u >> 16) & 1u)) >> 16;
  return (short)r;
}
__device__ __forceinline__ float bf2f(short v) {
  return __uint_as_float(((unsigned)(unsigned short)v) << 16);
}

// ---------------------------------------------------------------------------
// kPre: one pass over x. Produces:
//   xbf (B,L,D) bf16 ; xT (B,D,L) bf16 ; s[b,d]=sum_l x (atomic, bf16-sourced);
//   c[b,l]=dot(x[l,b,:],Wb) (atomic, fp32-sourced)
// ---------------------------------------------------------------------------
__global__ __launch_bounds__(256) void kPre(const float* __restrict__ x,
                                            const float* __restrict__ Wb,
                                            short* __restrict__ xbf,
                                            short* __restrict__ xT,
                                            float* __restrict__ s,
                                            float* __restrict__ c) {
  const int l0 = blockIdx.x * 64, d0 = blockIdx.y * 64, b = blockIdx.z;
  __shared__ short tile[64 * 72];  // tile[d_local][l_local], stride 72
  const int tid = threadIdx.x;
  const int r = tid >> 2;
  const int q = tid & 3;
  const int c0 = q * 16;

  short sv[16];
  float cpart = 0.f;
  const float* src = x + (size_t)(l0 + r) * BD + b * D_ + d0 + c0;
#pragma unroll
  for (int qq = 0; qq < 4; ++qq) {
    float4 f = *(const float4*)(src + qq * 4);
    const float* wb = Wb + d0 + c0 + qq * 4;
    cpart += f.x * wb[0] + f.y * wb[1] + f.z * wb[2] + f.w * wb[3];
    sv[qq * 4 + 0] = f2bf(f.x); sv[qq * 4 + 1] = f2bf(f.y);
    sv[qq * 4 + 2] = f2bf(f.z); sv[qq * 4 + 3] = f2bf(f.w);
  }
  short* dst = xbf + ((size_t)b * L_ + l0 + r) * D_ + d0 + c0;
  *(short8*)(dst)     = *(short8*)(sv);
  *(short8*)(dst + 8) = *(short8*)(sv + 8);
#pragma unroll
  for (int i = 0; i < 16; ++i) tile[(c0 + i) * 72 + r] = sv[i];
  cpart += __shfl_xor(cpart, 1);
  cpart += __shfl_xor(cpart, 2);
  if (q == 0) atomicAdd(&c[b * L_ + l0 + r], cpart);
  __syncthreads();
  short8 t0 = *(const short8*)(tile + r * 72 + c0);
  short8 t1 = *(const short8*)(tile + r * 72 + c0 + 8);
  short* tdst = xT + ((size_t)b * D_ + d0 + r) * L_ + l0 + c0;
  *(short8*)(tdst)     = t0;
  *(short8*)(tdst + 8) = t1;
  float spart = 0.f;
#pragma unroll
  for (int i = 0; i < 8; ++i) spart += bf2f(t0[i]) + bf2f(t1[i]);
  spart += __shfl_xor(spart, 1);
  spart += __shfl_xor(spart, 2);
  if (q == 0) atomicAdd(&s[b * D_ + d0 + r], spart);
}

// ---------------------------------------------------------------------------
// kCastW: Ww -> Wwb (bf16), Lw -> Lwb (bf16, VP rows, zero-pad v>=V_)
// ---------------------------------------------------------------------------
__global__ __launch_bounds__(256) void kCastW(const float* __restrict__ Ww,
                                              const float* __restrict__ Lw,
                                              short* __restrict__ Wwb,
                                              short* __restrict__ Lwb) {
  const int idx = blockIdx.x * 256 + threadIdx.x;  // quad index
  if (idx < 65536) {
    const int e = idx * 4;
    float4 f = *(const float4*)(Ww + e);
    short4v o; o[0] = f2bf(f.x); o[1] = f2bf(f.y); o[2] = f2bf(f.z); o[3] = f2bf(f.w);
    *(short4v*)(Wwb + e) = o;
  } else {
    const int e = (idx - 65536) * 4;
    const int v = e >> 9;
    short4v o = {};
    if (v < V_) {
      float4 f = *(const float4*)(Lw + e);
      o[0] = f2bf(f.x); o[1] = f2bf(f.y); o[2] = f2bf(f.z); o[3] = f2bf(f.w);
    }
    *(short4v*)(Lwb + e) = o;
  }
}

// ---------------------------------------------------------------------------
// kT: t[b][v] = dot(Lw[v,:], s[b,:]); v >= V_ -> 0
// ---------------------------------------------------------------------------
__global__ __launch_bounds__(256) void kT(const float* __restrict__ Lw,
                                          const float* __restrict__ s,
                                          float* __restrict__ t) {
  const int w = threadIdx.x >> 6, lane = threadIdx.x & 63;
  const int wid = blockIdx.x * 4 + w;
  const int b = wid >> 10, v = wid & 1023;
  float sum = 0.f;
  if (v < V_) {
    const float* lr = Lw + (size_t)v * D_;
    const float* sb = s + b * D_;
#pragma unroll
    for (int i = 0; i < 8; ++i) sum += lr[lane + i * 64] * sb[lane + i * 64];
  }
  for (int off = 32; off; off >>= 1) sum += __shfl_down(sum, off);
  if (lane == 0) t[b * VP + v] = (v < V_) ? sum : 0.f;
}

// ---------------------------------------------------------------------------
// kGbf: Gpart[z] = xT_b[:,chunk] . xT_b[:,chunk]^T  (bf16 out, 128x128 tiles)
// ---------------------------------------------------------------------------
__global__ __launch_bounds__(256) void kGbf(const short* __restrict__ xT,
                                            short* __restrict__ Gpart) {
  const int z = blockIdx.z;
  const int b = z >> 3, ch = z & 7;
  const int i0 = blockIdx.x * 128, j0 = blockIdx.y * 128;
  const short* Ab = xT + (size_t)b * D_ * L_;
  __shared__ short As[128 * 64];
  __shared__ short Bs[128 * 64];
  f32x4 acc[4][4] = {};
  const int tid = threadIdx.x;
  const int w = tid >> 6, lane = tid & 63;
  const int quad = lane >> 4, mcol = lane & 15;
  const int wr0 = (w & 1) * 64, wc0 = (w >> 1) * 64;
  const int kbase = ch * 512;

  for (int k0 = kbase; k0 < kbase + 512; k0 += 64) {
#pragma unroll
    for (int q = 0; q < 4; ++q) {
      const int u = q * 256 + tid;
      const int row = u >> 3, blk = u & 7;
      const int phys = blk ^ (row & 7);
      *(short8*)(As + row * 64 + phys * 8) =
          *(const short8*)(Ab + (size_t)(i0 + row) * L_ + k0 + blk * 8);
      *(short8*)(Bs + row * 64 + phys * 8) =
          *(const short8*)(Ab + (size_t)(j0 + row) * L_ + k0 + blk * 8);
    }
    __syncthreads();
#pragma unroll
    for (int ss = 0; ss < 2; ++ss) {
      short8 af[4], bf[4];
#pragma unroll
      for (int i = 0; i < 4; ++i) {
        const int arow = wr0 + i * 16 + mcol;
        const int ablk = (ss * 4 + quad) ^ (arow & 7);
        af[i] = *(const short8*)(As + arow * 64 + ablk * 8);
        const int brow = wc0 + i * 16 + mcol;
        const int bblk = (ss * 4 + quad) ^ (brow & 7);
        bf[i] = *(const short8*)(Bs + brow * 64 + bblk * 8);
      }
#pragma unroll
      for (int i = 0; i < 4; ++i)
#pragma unroll
        for (int j = 0; j < 4; ++j)
          acc[i][j] = __builtin_amdgcn_mfma_f32_16x16x32_bf16(af[i], bf[j],
                                                              acc[i][j], 0, 0, 0);
    }
    __syncthreads();
  }
  short* Gp = Gpart + (size_t)z * (D_ * D_);
#pragma unroll
  for (int i = 0; i < 4; ++i)
#pragma unroll
    for (int j = 0; j < 4; ++j) {
      const int col = j0 + wc0 + j * 16 + mcol;
#pragma unroll
      for (int r = 0; r < 4; ++r) {
        const int rowi = i0 + wr0 + i * 16 + quad * 4 + r;
        Gp[(size_t)rowi * D_ + col] = f2bf(acc[i][j][r]);
      }
    }
}

// ---------------------------------------------------------------------------
// kGreduce: Gb = sum_ch Gpart (bf16 in, bf16 out)
// ---------------------------------------------------------------------------
__global__ __launch_bounds__(256) void kGreduce(const short* __restrict__ Gpart,
                                                short* __restrict__ Gb) {
  const int idx = blockIdx.x * 256 + threadIdx.x;  // short8 index
  const int b = idx >> 15, e = (idx & 32767) * 8;
  float sum[8] = {};
#pragma unroll
  for (int ch = 0; ch < NCH; ++ch) {
    short8 v = *(const short8*)(Gpart + ((size_t)(b * NCH + ch)) * (D_ * D_) + e);
#pragma unroll
    for (int i = 0; i < 8; ++i) sum[i] += bf2f(v[i]);
  }
  short8 o;
#pragma unroll
  for (int i = 0; i < 8; ++i) o[i] = f2bf(sum[i]);
  *(short8*)(Gb + (size_t)b * (D_ * D_) + e) = o;
}

// ---------------------------------------------------------------------------
// kMbf: Mb[b] = Wwb @ Gb[b]  (G symmetric -> B operand = Gb rows), bf16 out
// ---------------------------------------------------------------------------
__global__ __launch_bounds__(256) void kMbf(const short* __restrict__ Wwb,
                                            const short* __restrict__ Gb,
                                            short* __restrict__ Mb) {
  const int b = blockIdx.z;
  const int i0 = blockIdx.x * 128, j0 = blockIdx.y * 128;
  const short* Bbase = Gb + (size_t)b * D_ * D_;
  __shared__ short As[128 * 64];
  __shared__ short Bs[128 * 64];
  f32x4 acc[4][4] = {};
  const int tid = threadIdx.x;
  const int w = tid >> 6, lane = tid & 63;
  const int quad = lane >> 4, mcol = lane & 15;
  const int wr0 = (w & 1) * 64, wc0 = (w >> 1) * 64;

  for (int k0 = 0; k0 < D_; k0 += 64) {
#pragma unroll
    for (int q = 0; q < 4; ++q) {
      const int u = q * 256 + tid;
      const int row = u >> 3, blk = u & 7;
      const int phys = blk ^ (row & 7);
      *(short8*)(As + row * 64 + phys * 8) =
          *(const short8*)(Wwb + (size_t)(i0 + row) * D_ + k0 + blk * 8);
      *(short8*)(Bs + row * 64 + phys * 8) =
          *(const short8*)(Bbase + (size_t)(j0 + row) * D_ + k0 + blk * 8);
    }
    __syncthreads();
#pragma unroll
    for (int ss = 0; ss < 2; ++ss) {
      short8 af[4], bf[4];
#pragma unroll
      for (int i = 0; i < 4; ++i) {
        const int arow = wr0 + i * 16 + mcol;
        const int ablk = (ss * 4 + quad) ^ (arow & 7);
        af[i] = *(const short8*)(As + arow * 64 + ablk * 8);
        const int brow = wc0 + i * 16 + mcol;
        const int bblk = (ss * 4 + quad) ^ (brow & 7);
        bf[i] = *(const short8*)(Bs + brow * 64 + bblk * 8);
      }
#pragma unroll
      for (int i = 0; i < 4; ++i)
#pragma unroll
        for (int j = 0; j < 4; ++j)
          acc[i][j] = __builtin_amdgcn_mfma_f32_16x16x32_bf16(af[i], bf[j],
                                                              acc[i][j], 0, 0, 0);
    }
    __syncthreads();
  }
  short* Mo = Mb + (size_t)b * D_ * D_;
#pragma unroll
  for (int i = 0; i < 4; ++i)
#pragma unroll
    for (int j = 0; j < 4; ++j) {
      const int col = j0 + wc0 + j * 16 + mcol;
#pragma unroll
      for (int r = 0; r < 4; ++r) {
        const int rowi = i0 + wr0 + i * 16 + quad * 4 + r;
        Mo[(size_t)rowi * D_ + col] = f2bf(acc[i][j][r]);
      }
    }
}

// ---------------------------------------------------------------------------
// kPbf: Ptb[b][v][d] = sum_j Lwb[v,j] * Mb[b][d,j]  (bf16 MFMA, bf16 out)
// ---------------------------------------------------------------------------
__global__ __launch_bounds__(256) void kPbf(const short* __restrict__ Lwb,
                                            const short* __restrict__ Mb,
                                            short* __restrict__ Ptb) {
  const int b = blockIdx.z;
  const int i0 = blockIdx.x * 128;  // v
  const int j0 = blockIdx.y * 128;  // d
  const short* Bbase = Mb + (size_t)b * D_ * D_;
  __shared__ short As[128 * 64];
  __shared__ short Bs[128 * 64];
  f32x4 acc[4][4] = {};
  const int tid = threadIdx.x;
  const int w = tid >> 6, lane = tid & 63;
  const int quad = lane >> 4, mcol = lane & 15;
  const int wr0 = (w & 1) * 64, wc0 = (w >> 1) * 64;

  for (int k0 = 0; k0 < D_; k0 += 64) {
#pragma unroll
    for (int q = 0; q < 4; ++q) {
      const int u = q * 256 + tid;
      const int row = u >> 3, blk = u & 7;
      const int phys = blk ^ (row & 7);
      *(short8*)(As + row * 64 + phys * 8) =
          *(const short8*)(Lwb + (size_t)(i0 + row) * D_ + k0 + blk * 8);
      *(short8*)(Bs + row * 64 + phys * 8) =
          *(const short8*)(Bbase + (size_t)(j0 + row) * D_ + k0 + blk * 8);
    }
    __syncthreads();
#pragma unroll
    for (int ss = 0; ss < 2; ++ss) {
      short8 af[4], bf[4];
#pragma unroll
      for (int i = 0; i < 4; ++i) {
        const int arow = wr0 + i * 16 + mcol;
        const int ablk = (ss * 4 + quad) ^ (arow & 7);
        af[i] = *(const short8*)(As + arow * 64 + ablk * 8);
        const int brow = wc0 + i * 16 + mcol;
        const int bblk = (ss * 4 + quad) ^ (brow & 7);
        bf[i] = *(const short8*)(Bs + brow * 64 + bblk * 8);
      }
#pragma unroll
      for (int i = 0; i < 4; ++i)
#pragma unroll
        for (int j = 0; j < 4; ++j)
          acc[i][j] = __builtin_amdgcn_mfma_f32_16x16x32_bf16(af[i], bf[j],
                                                              acc[i][j], 0, 0, 0);
    }
    __syncthreads();
  }
  short* Po = Ptb + (size_t)b * VP * D_;
#pragma unroll
  for (int i = 0; i < 4; ++i)
#pragma unroll
    for (int j = 0; j < 4; ++j) {
      const int col = j0 + wc0 + j * 16 + mcol;
#pragma unroll
      for (int r = 0; r < 4; ++r) {
        const int rowi = i0 + wr0 + i * 16 + quad * 4 + r;
        Po[(size_t)rowi * D_ + col] = f2bf(acc[i][j][r]);
      }
    }
}

// ---------------------------------------------------------------------------
// kOut: fused logits + log_softmax, writes final output (L,B,V) fp32.
// Block: 512 threads (8 waves). Tile: 32 l-rows x VP vocab. Wave w owns the
// 128-v stripe [w*128, w*128+128). A (32x512) staged once in LDS (swizzled);
// B (Ptb rows) read straight from global (L2-resident, 1 MB/batch).
// ---------------------------------------------------------------------------
__global__ __launch_bounds__(512) void kOut(const short* __restrict__ xbf,
                                            const short* __restrict__ Ptb,
                                            const float* __restrict__ c,
                                            const float* __restrict__ t,
                                            const float* __restrict__ Lb,
                                            float* __restrict__ out) {
  const int b = blockIdx.y;
  const int l0 = blockIdx.x * 32;
  const short* Abase = xbf + ((size_t)b * L_ + l0) * D_;
  const short* Bbase = Ptb + (size_t)b * VP * D_;
  __shared__ short As[32 * 512];  // 32 KB
  __shared__ float red_m[32][8];
  __shared__ float red_s[32][8];
  const int tid = threadIdx.x;
  const int w = tid >> 6, lane = tid & 63;
  const int quad = lane >> 4, mcol = lane & 15;
  const int v0 = w * 128;

  // stage A: full 32 x 512 block, XOR-swizzled within each row
  for (int ci = tid; ci < 2048; ci += 512) {
    const int row = ci >> 6, blk = ci & 63;
    const int phys = blk ^ (row & 7);
    *(short8*)(As + row * 512 + phys * 8) =
        *(const short8*)(Abase + (size_t)row * D_ + blk * 8);
  }
  __syncthreads();

  f32x4 acc[2][8] = {};
  for (int ks = 0; ks < 16; ++ks) {
    const int k0 = ks * 32;
    short8 bfr[8];
#pragma unroll
    for (int j = 0; j < 8; ++j)
      bfr[j] = *(const short8*)(Bbase +
                                (size_t)(v0 + j * 16 + mcol) * D_ + k0 + quad * 8);
    short8 af[2];
#pragma unroll
    for (int i = 0; i < 2; ++i) {
      const int arow = i * 16 + mcol;
      const int ablk = (ks * 4 + quad) ^ (arow & 7);
      af[i] = *(const short8*)(As + arow * 512 + ablk * 8);
    }
#pragma unroll
    for (int i = 0; i < 2; ++i)
#pragma unroll
      for (int j = 0; j < 8; ++j)
        acc[i][j] = __builtin_amdgcn_mfma_f32_16x16x32_bf16(af[i], bfr[j],
                                                            acc[i][j], 0, 0, 0);
  }

  // epilogue: logits in-place (acc := acc + c*t + Lb), then log-softmax
  float cv[2][4];
#pragma unroll
  for (int i = 0; i < 2; ++i)
#pragma unroll
    for (int r = 0; r < 4; ++r)
      cv[i][r] = c[b * L_ + l0 + i * 16 + quad * 4 + r];
  float tv[8], lbv[8];
  bool valid[8];
#pragma unroll
  for (int j = 0; j < 8; ++j) {
    const int gv = v0 + j * 16 + mcol;
    tv[j] = t[b * VP + gv];
    valid[j] = gv < V_;
    lbv[j] = valid[j] ? Lb[gv] : 0.f;
  }
#pragma unroll
  for (int i = 0; i < 2; ++i)
#pragma unroll
    for (int j = 0; j < 8; ++j)
#pragma unroll
      for (int r = 0; r < 4; ++r)
        acc[i][j][r] += cv[i][r] * tv[j] + lbv[j];

  // per-row max & sumexp within this wave's 128-v stripe
#pragma unroll
  for (int i = 0; i < 2; ++i)
#pragma unroll
    for (int r = 0; r < 4; ++r) {
      float m = -__builtin_inff();
#pragma unroll
      for (int j = 0; j < 8; ++j)
        if (valid[j]) m = fmaxf(m, acc[i][j][r]);
      for (int off = 1; off <= 8; off <<= 1) m = fmaxf(m, __shfl_xor(m, off));
      float sse = 0.f;
#pragma unroll
      for (int j = 0; j < 8; ++j)
        if (valid[j]) sse += expf(acc[i][j][r] - m);
      for (int off = 1; off <= 8; off <<= 1) sse += __shfl_xor(sse, off);
      if (mcol == 0) {
        const int row = i * 16 + quad * 4 + r;
        red_m[row][w] = m;
        red_s[row][w] = sse;
      }
    }
  __syncthreads();

  // combine across the 8 waves, write output
#pragma unroll
  for (int i = 0; i < 2; ++i)
#pragma unroll
    for (int r = 0; r < 4; ++r) {
      const int row = i * 16 + quad * 4 + r;
      float M = -__builtin_inff();
#pragma unroll
      for (int ww = 0; ww < 8; ++ww) M = fmaxf(M, red_m[row][ww]);
      float S = 0.f;
#pragma unroll
      for (int ww = 0; ww < 8; ++ww) S += red_s[row][ww] * expf(red_m[row][ww] - M);
      const float lse = M + logf(S);
      float* orow = out + (size_t)(l0 + row) * OUT_BV + b * V_;
#pragma unroll
      for (int j = 0; j < 8; ++j)
        if (valid[j]) orow[v0 + j * 16 + mcol] = acc[i][j][r] - lse;
    }
}

// ---------------------------------------------------------------------------
extern "C" void kernel_launch(void* const* d_in, const int* in_sizes, int n_in,
                              void* d_out, int out_size, void* d_ws,
                              size_t ws_size, hipStream_t stream) {
  const float* x  = (const float*)d_in[0];
  const float* Ww = (const float*)d_in[1];
  const float* Wb = (const float*)d_in[2];
  const float* Lw = (const float*)d_in[3];
  const float* Lb = (const float*)d_in[4];

  char* wp = (char*)d_ws;
  short* xbf = (short*)wp;   wp += (size_t)B_ * L_ * D_ * 2;        // 16 MB
  short* xT  = (short*)wp;   wp += (size_t)B_ * L_ * D_ * 2;        // 16 MB
  short* Ptb = (short*)wp;   wp += (size_t)B_ * VP * D_ * 2;        // 4 MB
  short* Gpart = (short*)wp; wp += (size_t)B_ * NCH * D_ * D_ * 2;  // 16 MB
  short* Gb  = (short*)wp;   wp += (size_t)B_ * D_ * D_ * 2;        // 2 MB
  short* Mb  = (short*)wp;   wp += (size_t)B_ * D_ * D_ * 2;        // 2 MB
  short* Wwb = (short*)wp;   wp += (size_t)D_ * D_ * 2;             // 0.5 MB
  short* Lwb = (short*)wp;   wp += (size_t)VP * D_ * 2;             // 1 MB
  float* s   = (float*)wp;   wp += (size_t)B_ * D_ * 4;             // 8 KB
  float* c   = (float*)wp;   wp += (size_t)B_ * L_ * 4;             // 64 KB
  float* t   = (float*)wp;   wp += (size_t)B_ * VP * 4;             // 16 KB

  // zero the atomic accumulators (s and c are contiguous)
  hipMemsetAsync(s, 0, (size_t)(B_ * D_ + B_ * L_) * sizeof(float), stream);

  kCastW<<<dim3(768), 256, 0, stream>>>(Ww, Lw, Wwb, Lwb);
  kPre<<<dim3(64, 8, B_), 256, 0, stream>>>(x, Wb, xbf, xT, s, c);
  kGbf<<<dim3(4, 4, B_ * NCH), 256, 0, stream>>>(xT, Gpart);
  kGreduce<<<dim3(512), 256, 0, stream>>>(Gpart, Gb);
  kMbf<<<dim3(4, 4, B_), 256, 0, stream>>>(Wwb, Gb, Mb);
  kT<<<dim3(1024), 256, 0, stream>>>(Lw, s, t);
  kPbf<<<dim3(8, 4, B_), 256, 0, stream>>>(Lwb, Mb, Ptb);
  kOut<<<dim3(L_ / 32, B_), 512, 0, stream>>>(xbf, Ptb, c, t, Lb, (float*)d_out);
}

// Round 5
// 217.656 us; speedup vs baseline: 1.0917x; 1.0917x over previous
//
#include <hip/hip_runtime.h>
#include <math.h>

#define L_ 4096
#define B_ 4
#define D_ 512
#define V_ 1000
#define VP 1024
#define BD 2048     // B_*D_
#define OUT_BV 4000 // B_*V_
#define NCH 8       // split-K chunks for kGbf

typedef __attribute__((ext_vector_type(8))) short short8;
typedef __attribute__((ext_vector_type(4))) float f32x4;
typedef __attribute__((ext_vector_type(4))) short short4v;

__device__ __forceinline__ short f2bf(float f) {
  unsigned u = __float_as_uint(f);
  unsigned r = (u + 0x7FFFu + ((u >> 16) & 1u)) >> 16;
  return (short)r;
}
__device__ __forceinline__ float bf2f(short v) {
  return __uint_as_float(((unsigned)(unsigned short)v) << 16);
}

// ---------------------------------------------------------------------------
// kPre: one pass over x. Produces:
//   xbf (B,L,D) bf16 ; xT (B,D,L) bf16 ; s[b,d]=sum_l x (atomic);
//   c[b,l]=dot(x[l,b,:],Wb) (atomic)
// ---------------------------------------------------------------------------
__global__ __launch_bounds__(256) void kPre(const float* __restrict__ x,
                                            const float* __restrict__ Wb,
                                            short* __restrict__ xbf,
                                            short* __restrict__ xT,
                                            float* __restrict__ s,
                                            float* __restrict__ c) {
  const int l0 = blockIdx.x * 64, d0 = blockIdx.y * 64, b = blockIdx.z;
  __shared__ short tile[64 * 72];  // tile[d_local][l_local], stride 72
  const int tid = threadIdx.x;
  const int r = tid >> 2;
  const int q = tid & 3;
  const int c0 = q * 16;

  short sv[16];
  float cpart = 0.f;
  const float* src = x + (size_t)(l0 + r) * BD + b * D_ + d0 + c0;
#pragma unroll
  for (int qq = 0; qq < 4; ++qq) {
    float4 f = *(const float4*)(src + qq * 4);
    const float* wb = Wb + d0 + c0 + qq * 4;
    cpart += f.x * wb[0] + f.y * wb[1] + f.z * wb[2] + f.w * wb[3];
    sv[qq * 4 + 0] = f2bf(f.x); sv[qq * 4 + 1] = f2bf(f.y);
    sv[qq * 4 + 2] = f2bf(f.z); sv[qq * 4 + 3] = f2bf(f.w);
  }
  short* dst = xbf + ((size_t)b * L_ + l0 + r) * D_ + d0 + c0;
  *(short8*)(dst)     = *(short8*)(sv);
  *(short8*)(dst + 8) = *(short8*)(sv + 8);
#pragma unroll
  for (int i = 0; i < 16; ++i) tile[(c0 + i) * 72 + r] = sv[i];
  cpart += __shfl_xor(cpart, 1);
  cpart += __shfl_xor(cpart, 2);
  if (q == 0) atomicAdd(&c[b * L_ + l0 + r], cpart);
  __syncthreads();
  short8 t0 = *(const short8*)(tile + r * 72 + c0);
  short8 t1 = *(const short8*)(tile + r * 72 + c0 + 8);
  short* tdst = xT + ((size_t)b * D_ + d0 + r) * L_ + l0 + c0;
  *(short8*)(tdst)     = t0;
  *(short8*)(tdst + 8) = t1;
  float spart = 0.f;
#pragma unroll
  for (int i = 0; i < 8; ++i) spart += bf2f(t0[i]) + bf2f(t1[i]);
  spart += __shfl_xor(spart, 1);
  spart += __shfl_xor(spart, 2);
  if (q == 0) atomicAdd(&s[b * D_ + d0 + r], spart);
}

// ---------------------------------------------------------------------------
// kCastW: Ww -> Wwb (bf16), Lw -> Lwb (bf16, VP rows, zero-pad v>=V_)
// ---------------------------------------------------------------------------
__global__ __launch_bounds__(256) void kCastW(const float* __restrict__ Ww,
                                              const float* __restrict__ Lw,
                                              short* __restrict__ Wwb,
                                              short* __restrict__ Lwb) {
  const int idx = blockIdx.x * 256 + threadIdx.x;  // quad index
  if (idx < 65536) {
    const int e = idx * 4;
    float4 f = *(const float4*)(Ww + e);
    short4v o; o[0] = f2bf(f.x); o[1] = f2bf(f.y); o[2] = f2bf(f.z); o[3] = f2bf(f.w);
    *(short4v*)(Wwb + e) = o;
  } else {
    const int e = (idx - 65536) * 4;
    const int v = e >> 9;
    short4v o = {};
    if (v < V_) {
      float4 f = *(const float4*)(Lw + e);
      o[0] = f2bf(f.x); o[1] = f2bf(f.y); o[2] = f2bf(f.z); o[3] = f2bf(f.w);
    }
    *(short4v*)(Lwb + e) = o;
  }
}

// ---------------------------------------------------------------------------
// kT: t[b][v] = dot(Lw[v,:], s[b,:]); v >= V_ -> 0
// ---------------------------------------------------------------------------
__global__ __launch_bounds__(256) void kT(const float* __restrict__ Lw,
                                          const float* __restrict__ s,
                                          float* __restrict__ t) {
  const int w = threadIdx.x >> 6, lane = threadIdx.x & 63;
  const int wid = blockIdx.x * 4 + w;
  const int b = wid >> 10, v = wid & 1023;
  float sum = 0.f;
  if (v < V_) {
    const float* lr = Lw + (size_t)v * D_;
    const float* sb = s + b * D_;
#pragma unroll
    for (int i = 0; i < 8; ++i) sum += lr[lane + i * 64] * sb[lane + i * 64];
  }
  for (int off = 32; off; off >>= 1) sum += __shfl_down(sum, off);
  if (lane == 0) t[b * VP + v] = (v < V_) ? sum : 0.f;
}

// ---------------------------------------------------------------------------
// kGbf: Gpart[z] = xT_b[:,chunk] . xT_b[:,chunk]^T  (bf16 out, 128x128 tiles)
// ---------------------------------------------------------------------------
__global__ __launch_bounds__(256) void kGbf(const short* __restrict__ xT,
                                            short* __restrict__ Gpart) {
  const int z = blockIdx.z;
  const int b = z >> 3, ch = z & 7;
  const int i0 = blockIdx.x * 128, j0 = blockIdx.y * 128;
  const short* Ab = xT + (size_t)b * D_ * L_;
  __shared__ short As[128 * 64];
  __shared__ short Bs[128 * 64];
  f32x4 acc[4][4] = {};
  const int tid = threadIdx.x;
  const int w = tid >> 6, lane = tid & 63;
  const int quad = lane >> 4, mcol = lane & 15;
  const int wr0 = (w & 1) * 64, wc0 = (w >> 1) * 64;
  const int kbase = ch * 512;

  for (int k0 = kbase; k0 < kbase + 512; k0 += 64) {
#pragma unroll
    for (int q = 0; q < 4; ++q) {
      const int u = q * 256 + tid;
      const int row = u >> 3, blk = u & 7;
      const int phys = blk ^ (row & 7);
      *(short8*)(As + row * 64 + phys * 8) =
          *(const short8*)(Ab + (size_t)(i0 + row) * L_ + k0 + blk * 8);
      *(short8*)(Bs + row * 64 + phys * 8) =
          *(const short8*)(Ab + (size_t)(j0 + row) * L_ + k0 + blk * 8);
    }
    __syncthreads();
#pragma unroll
    for (int ss = 0; ss < 2; ++ss) {
      short8 af[4], bf[4];
#pragma unroll
      for (int i = 0; i < 4; ++i) {
        const int arow = wr0 + i * 16 + mcol;
        const int ablk = (ss * 4 + quad) ^ (arow & 7);
        af[i] = *(const short8*)(As + arow * 64 + ablk * 8);
        const int brow = wc0 + i * 16 + mcol;
        const int bblk = (ss * 4 + quad) ^ (brow & 7);
        bf[i] = *(const short8*)(Bs + brow * 64 + bblk * 8);
      }
#pragma unroll
      for (int i = 0; i < 4; ++i)
#pragma unroll
        for (int j = 0; j < 4; ++j)
          acc[i][j] = __builtin_amdgcn_mfma_f32_16x16x32_bf16(af[i], bf[j],
                                                              acc[i][j], 0, 0, 0);
    }
    __syncthreads();
  }
  short* Gp = Gpart + (size_t)z * (D_ * D_);
#pragma unroll
  for (int i = 0; i < 4; ++i)
#pragma unroll
    for (int j = 0; j < 4; ++j) {
      const int col = j0 + wc0 + j * 16 + mcol;
#pragma unroll
      for (int r = 0; r < 4; ++r) {
        const int rowi = i0 + wr0 + i * 16 + quad * 4 + r;
        Gp[(size_t)rowi * D_ + col] = f2bf(acc[i][j][r]);
      }
    }
}

// ---------------------------------------------------------------------------
// kGreduce: Gb = sum_ch Gpart (bf16 in, bf16 out)
// ---------------------------------------------------------------------------
__global__ __launch_bounds__(256) void kGreduce(const short* __restrict__ Gpart,
                                                short* __restrict__ Gb) {
  const int idx = blockIdx.x * 256 + threadIdx.x;  // short8 index
  const int b = idx >> 15, e = (idx & 32767) * 8;
  float sum[8] = {};
#pragma unroll
  for (int ch = 0; ch < NCH; ++ch) {
    short8 v = *(const short8*)(Gpart + ((size_t)(b * NCH + ch)) * (D_ * D_) + e);
#pragma unroll
    for (int i = 0; i < 8; ++i) sum[i] += bf2f(v[i]);
  }
  short8 o;
#pragma unroll
  for (int i = 0; i < 8; ++i) o[i] = f2bf(sum[i]);
  *(short8*)(Gb + (size_t)b * (D_ * D_) + e) = o;
}

// ---------------------------------------------------------------------------
// kMbf: Mb[b] = Wwb @ Gb[b]  (G symmetric -> B operand = Gb rows), bf16 out
// ---------------------------------------------------------------------------
__global__ __launch_bounds__(256) void kMbf(const short* __restrict__ Wwb,
                                            const short* __restrict__ Gb,
                                            short* __restrict__ Mb) {
  const int b = blockIdx.z;
  const int i0 = blockIdx.x * 128, j0 = blockIdx.y * 128;
  const short* Bbase = Gb + (size_t)b * D_ * D_;
  __shared__ short As[128 * 64];
  __shared__ short Bs[128 * 64];
  f32x4 acc[4][4] = {};
  const int tid = threadIdx.x;
  const int w = tid >> 6, lane = tid & 63;
  const int quad = lane >> 4, mcol = lane & 15;
  const int wr0 = (w & 1) * 64, wc0 = (w >> 1) * 64;

  for (int k0 = 0; k0 < D_; k0 += 64) {
#pragma unroll
    for (int q = 0; q < 4; ++q) {
      const int u = q * 256 + tid;
      const int row = u >> 3, blk = u & 7;
      const int phys = blk ^ (row & 7);
      *(short8*)(As + row * 64 + phys * 8) =
          *(const short8*)(Wwb + (size_t)(i0 + row) * D_ + k0 + blk * 8);
      *(short8*)(Bs + row * 64 + phys * 8) =
          *(const short8*)(Bbase + (size_t)(j0 + row) * D_ + k0 + blk * 8);
    }
    __syncthreads();
#pragma unroll
    for (int ss = 0; ss < 2; ++ss) {
      short8 af[4], bf[4];
#pragma unroll
      for (int i = 0; i < 4; ++i) {
        const int arow = wr0 + i * 16 + mcol;
        const int ablk = (ss * 4 + quad) ^ (arow & 7);
        af[i] = *(const short8*)(As + arow * 64 + ablk * 8);
        const int brow = wc0 + i * 16 + mcol;
        const int bblk = (ss * 4 + quad) ^ (brow & 7);
        bf[i] = *(const short8*)(Bs + brow * 64 + bblk * 8);
      }
#pragma unroll
      for (int i = 0; i < 4; ++i)
#pragma unroll
        for (int j = 0; j < 4; ++j)
          acc[i][j] = __builtin_amdgcn_mfma_f32_16x16x32_bf16(af[i], bf[j],
                                                              acc[i][j], 0, 0, 0);
    }
    __syncthreads();
  }
  short* Mo = Mb + (size_t)b * D_ * D_;
#pragma unroll
  for (int i = 0; i < 4; ++i)
#pragma unroll
    for (int j = 0; j < 4; ++j) {
      const int col = j0 + wc0 + j * 16 + mcol;
#pragma unroll
      for (int r = 0; r < 4; ++r) {
        const int rowi = i0 + wr0 + i * 16 + quad * 4 + r;
        Mo[(size_t)rowi * D_ + col] = f2bf(acc[i][j][r]);
      }
    }
}

// ---------------------------------------------------------------------------
// kPbf: Ptb[b][v][d] = sum_j Lwb[v,j] * Mb[b][d,j]  (bf16 MFMA, bf16 out)
// ---------------------------------------------------------------------------
__global__ __launch_bounds__(256) void kPbf(const short* __restrict__ Lwb,
                                            const short* __restrict__ Mb,
                                            short* __restrict__ Ptb) {
  const int b = blockIdx.z;
  const int i0 = blockIdx.x * 128;  // v
  const int j0 = blockIdx.y * 128;  // d
  const short* Bbase = Mb + (size_t)b * D_ * D_;
  __shared__ short As[128 * 64];
  __shared__ short Bs[128 * 64];
  f32x4 acc[4][4] = {};
  const int tid = threadIdx.x;
  const int w = tid >> 6, lane = tid & 63;
  const int quad = lane >> 4, mcol = lane & 15;
  const int wr0 = (w & 1) * 64, wc0 = (w >> 1) * 64;

  for (int k0 = 0; k0 < D_; k0 += 64) {
#pragma unroll
    for (int q = 0; q < 4; ++q) {
      const int u = q * 256 + tid;
      const int row = u >> 3, blk = u & 7;
      const int phys = blk ^ (row & 7);
      *(short8*)(As + row * 64 + phys * 8) =
          *(const short8*)(Lwb + (size_t)(i0 + row) * D_ + k0 + blk * 8);
      *(short8*)(Bs + row * 64 + phys * 8) =
          *(const short8*)(Bbase + (size_t)(j0 + row) * D_ + k0 + blk * 8);
    }
    __syncthreads();
#pragma unroll
    for (int ss = 0; ss < 2; ++ss) {
      short8 af[4], bf[4];
#pragma unroll
      for (int i = 0; i < 4; ++i) {
        const int arow = wr0 + i * 16 + mcol;
        const int ablk = (ss * 4 + quad) ^ (arow & 7);
        af[i] = *(const short8*)(As + arow * 64 + ablk * 8);
        const int brow = wc0 + i * 16 + mcol;
        const int bblk = (ss * 4 + quad) ^ (brow & 7);
        bf[i] = *(const short8*)(Bs + brow * 64 + bblk * 8);
      }
#pragma unroll
      for (int i = 0; i < 4; ++i)
#pragma unroll
        for (int j = 0; j < 4; ++j)
          acc[i][j] = __builtin_amdgcn_mfma_f32_16x16x32_bf16(af[i], bf[j],
                                                              acc[i][j], 0, 0, 0);
    }
    __syncthreads();
  }
  short* Po = Ptb + (size_t)b * VP * D_;
#pragma unroll
  for (int i = 0; i < 4; ++i)
#pragma unroll
    for (int j = 0; j < 4; ++j) {
      const int col = j0 + wc0 + j * 16 + mcol;
#pragma unroll
      for (int r = 0; r < 4; ++r) {
        const int rowi = i0 + wr0 + i * 16 + quad * 4 + r;
        Po[(size_t)rowi * D_ + col] = f2bf(acc[i][j][r]);
      }
    }
}

// ---------------------------------------------------------------------------
// kLogits2: logits[b,l,v] = x[l]·Ptb[v] + c[b,l]*t[b,v] + Lb[v], bf16 out.
// OPERANDS SWAPPED vs round 3: A = Ptb (v-rows), B = xbf (l-rows), so the
// C fragment gives each lane 4 CONSECUTIVE v at one l -> vectorized stores.
// ---------------------------------------------------------------------------
__global__ __launch_bounds__(256) void kLogits2(const short* __restrict__ xbf,
                                                const short* __restrict__ Ptb,
                                                const float* __restrict__ c,
                                                const float* __restrict__ t,
                                                const float* __restrict__ Lb,
                                                short* __restrict__ logitsBf) {
  const int b = blockIdx.z;
  const int v0t = blockIdx.x * 128;  // v tile
  const int l0t = blockIdx.y * 128;  // l tile
  const short* Abase = Ptb + (size_t)b * VP * D_;
  const short* Bbase = xbf + (size_t)b * L_ * D_;
  __shared__ short As[128 * 64];
  __shared__ short Bs[128 * 64];
  f32x4 acc[4][4] = {};
  const int tid = threadIdx.x;
  const int w = tid >> 6, lane = tid & 63;
  const int quad = lane >> 4, mcol = lane & 15;
  const int wr0 = (w & 1) * 64, wc0 = (w >> 1) * 64;

  for (int k0 = 0; k0 < D_; k0 += 64) {
#pragma unroll
    for (int q = 0; q < 4; ++q) {
      const int u = q * 256 + tid;
      const int row = u >> 3, blk = u & 7;
      const int phys = blk ^ (row & 7);
      *(short8*)(As + row * 64 + phys * 8) =
          *(const short8*)(Abase + (size_t)(v0t + row) * D_ + k0 + blk * 8);
      *(short8*)(Bs + row * 64 + phys * 8) =
          *(const short8*)(Bbase + (size_t)(l0t + row) * D_ + k0 + blk * 8);
    }
    __syncthreads();
#pragma unroll
    for (int ss = 0; ss < 2; ++ss) {
      short8 af[4], bf[4];
#pragma unroll
      for (int i = 0; i < 4; ++i) {
        const int arow = wr0 + i * 16 + mcol;
        const int ablk = (ss * 4 + quad) ^ (arow & 7);
        af[i] = *(const short8*)(As + arow * 64 + ablk * 8);
        const int brow = wc0 + i * 16 + mcol;
        const int bblk = (ss * 4 + quad) ^ (brow & 7);
        bf[i] = *(const short8*)(Bs + brow * 64 + bblk * 8);
      }
#pragma unroll
      for (int i = 0; i < 4; ++i)
#pragma unroll
        for (int j = 0; j < 4; ++j)
          acc[i][j] = __builtin_amdgcn_mfma_f32_16x16x32_bf16(af[i], bf[j],
                                                              acc[i][j], 0, 0, 0);
    }
    __syncthreads();
  }
  // C[row=v][col=l]: lane (quad,mcol) reg r -> v = wr0+i*16+quad*4+r (consec),
  //                                           l = wc0+j*16+mcol
#pragma unroll
  for (int j = 0; j < 4; ++j) {
    const int gl = l0t + wc0 + j * 16 + mcol;
    const float cl = c[b * L_ + gl];
#pragma unroll
    for (int i = 0; i < 4; ++i) {
      const int gv0 = v0t + wr0 + i * 16 + quad * 4;
      f32x4 tv = *(const f32x4*)(t + b * VP + gv0);
      f32x4 lb4 = {};
      if (gv0 < V_) lb4 = *(const f32x4*)(Lb + gv0);  // V_ % 4 == 0
      short4v o;
#pragma unroll
      for (int r = 0; r < 4; ++r)
        o[r] = f2bf(acc[i][j][r] + cl * tv[r] + lb4[r]);
      *(short4v*)(logitsBf + ((size_t)b * L_ + gl) * VP + gv0) = o;
    }
  }
}

// ---------------------------------------------------------------------------
// kLsm: log_softmax over V per (b,l) row, bf16 logits in, fp32 out (L,B,V).
// One wave per row; no LDS, no barriers.
// ---------------------------------------------------------------------------
__global__ __launch_bounds__(256) void kLsm(const short* __restrict__ logitsBf,
                                            float* __restrict__ out) {
  const int b = blockIdx.y;
  const int l = blockIdx.x * 4 + (threadIdx.x >> 6);
  const int lane = threadIdx.x & 63;
  const short* row = logitsBf + ((size_t)b * L_ + l) * VP;
  short8 v0 = *(const short8*)(row + lane * 16);
  short8 v1 = *(const short8*)(row + lane * 16 + 8);
  float vals[16];
#pragma unroll
  for (int i = 0; i < 8; ++i) { vals[i] = bf2f(v0[i]); vals[8 + i] = bf2f(v1[i]); }
  float m = -__builtin_inff();
#pragma unroll
  for (int i = 0; i < 16; ++i)
    if (lane * 16 + i < V_) m = fmaxf(m, vals[i]);
  for (int off = 32; off; off >>= 1) m = fmaxf(m, __shfl_xor(m, off));
  float se = 0.f;
#pragma unroll
  for (int i = 0; i < 16; ++i)
    if (lane * 16 + i < V_) se += expf(vals[i] - m);
  for (int off = 32; off; off >>= 1) se += __shfl_xor(se, off);
  const float lse = m + logf(se);
  float* orow = out + (size_t)l * OUT_BV + b * V_;
#pragma unroll
  for (int q = 0; q < 4; ++q) {
    const int base = lane * 16 + q * 4;
    if (base < V_) {  // V_ % 4 == 0, so base<V_ implies base+3<V_
      float4 st = make_float4(vals[q * 4 + 0] - lse, vals[q * 4 + 1] - lse,
                              vals[q * 4 + 2] - lse, vals[q * 4 + 3] - lse);
      *(float4*)(orow + base) = st;
    }
  }
}

// ---------------------------------------------------------------------------
extern "C" void kernel_launch(void* const* d_in, const int* in_sizes, int n_in,
                              void* d_out, int out_size, void* d_ws,
                              size_t ws_size, hipStream_t stream) {
  const float* x  = (const float*)d_in[0];
  const float* Ww = (const float*)d_in[1];
  const float* Wb = (const float*)d_in[2];
  const float* Lw = (const float*)d_in[3];
  const float* Lb = (const float*)d_in[4];

  char* wp = (char*)d_ws;
  short* xbf = (short*)wp;   wp += (size_t)B_ * L_ * D_ * 2;        // 16 MB
  short* xT  = (short*)wp;   wp += (size_t)B_ * L_ * D_ * 2;        // 16 MB
  short* Ptb = (short*)wp;   wp += (size_t)B_ * VP * D_ * 2;        // 4 MB
  short* Gpart = (short*)wp; wp += (size_t)B_ * NCH * D_ * D_ * 2;  // 16 MB
  short* Gb  = (short*)wp;   wp += (size_t)B_ * D_ * D_ * 2;        // 2 MB
  short* Mb  = (short*)wp;   wp += (size_t)B_ * D_ * D_ * 2;        // 2 MB
  short* Wwb = (short*)wp;   wp += (size_t)D_ * D_ * 2;             // 0.5 MB
  short* Lwb = (short*)wp;   wp += (size_t)VP * D_ * 2;             // 1 MB
  float* s   = (float*)wp;   wp += (size_t)B_ * D_ * 4;             // 8 KB
  float* c   = (float*)wp;   wp += (size_t)B_ * L_ * 4;             // 64 KB
  float* t   = (float*)wp;   wp += (size_t)B_ * VP * 4;             // 16 KB
  short* logitsBf = (short*)wp;                                     // 32 MB

  // zero the atomic accumulators (s and c are contiguous)
  hipMemsetAsync(s, 0, (size_t)(B_ * D_ + B_ * L_) * sizeof(float), stream);

  kCastW<<<dim3(768), 256, 0, stream>>>(Ww, Lw, Wwb, Lwb);
  kPre<<<dim3(64, 8, B_), 256, 0, stream>>>(x, Wb, xbf, xT, s, c);
  kGbf<<<dim3(4, 4, B_ * NCH), 256, 0, stream>>>(xT, Gpart);
  kGreduce<<<dim3(512), 256, 0, stream>>>(Gpart, Gb);
  kMbf<<<dim3(4, 4, B_), 256, 0, stream>>>(Wwb, Gb, Mb);
  kT<<<dim3(1024), 256, 0, stream>>>(Lw, s, t);
  kPbf<<<dim3(8, 4, B_), 256, 0, stream>>>(Lwb, Mb, Ptb);
  kLogits2<<<dim3(8, 32, B_), 256, 0, stream>>>(xbf, Ptb, c, t, Lb, logitsBf);
  kLsm<<<dim3(L_ / 4, B_), 256, 0, stream>>>(logitsBf, (float*)d_out);
}

// Round 6
// 200.850 us; speedup vs baseline: 1.1830x; 1.0837x over previous
//
#include <hip/hip_runtime.h>
#include <math.h>

#define L_ 4096
#define B_ 4
#define D_ 512
#define V_ 1000
#define VP 1024
#define BD 2048     // B_*D_
#define OUT_BV 4000 // B_*V_
#define NCH 8       // split-K chunks for kGbf

typedef __attribute__((ext_vector_type(8))) short short8;
typedef __attribute__((ext_vector_type(4))) float f32x4;
typedef __attribute__((ext_vector_type(4))) short short4v;

__device__ __forceinline__ short f2bf(float f) {
  unsigned u = __float_as_uint(f);
  unsigned r = (u + 0x7FFFu + ((u >> 16) & 1u)) >> 16;
  return (short)r;
}
__device__ __forceinline__ float bf2f(short v) {
  return __uint_as_float(((unsigned)(unsigned short)v) << 16);
}

// ---------------------------------------------------------------------------
// kPre: one pass over x. Produces:
//   xbf (B,L,D) bf16 ; xT (B,D,L) bf16 ; s[b,d]=sum_l x (atomic);
//   c[b,l]=dot(x[l,b,:],Wb) (atomic)
// ---------------------------------------------------------------------------
__global__ __launch_bounds__(256) void kPre(const float* __restrict__ x,
                                            const float* __restrict__ Wb,
                                            short* __restrict__ xbf,
                                            short* __restrict__ xT,
                                            float* __restrict__ s,
                                            float* __restrict__ c) {
  const int l0 = blockIdx.x * 64, d0 = blockIdx.y * 64, b = blockIdx.z;
  __shared__ short tile[64 * 72];  // tile[d_local][l_local], stride 72
  const int tid = threadIdx.x;
  const int r = tid >> 2;
  const int q = tid & 3;
  const int c0 = q * 16;

  short sv[16];
  float cpart = 0.f;
  const float* src = x + (size_t)(l0 + r) * BD + b * D_ + d0 + c0;
#pragma unroll
  for (int qq = 0; qq < 4; ++qq) {
    float4 f = *(const float4*)(src + qq * 4);
    const float* wb = Wb + d0 + c0 + qq * 4;
    cpart += f.x * wb[0] + f.y * wb[1] + f.z * wb[2] + f.w * wb[3];
    sv[qq * 4 + 0] = f2bf(f.x); sv[qq * 4 + 1] = f2bf(f.y);
    sv[qq * 4 + 2] = f2bf(f.z); sv[qq * 4 + 3] = f2bf(f.w);
  }
  short* dst = xbf + ((size_t)b * L_ + l0 + r) * D_ + d0 + c0;
  *(short8*)(dst)     = *(short8*)(sv);
  *(short8*)(dst + 8) = *(short8*)(sv + 8);
#pragma unroll
  for (int i = 0; i < 16; ++i) tile[(c0 + i) * 72 + r] = sv[i];
  cpart += __shfl_xor(cpart, 1);
  cpart += __shfl_xor(cpart, 2);
  if (q == 0) atomicAdd(&c[b * L_ + l0 + r], cpart);
  __syncthreads();
  short8 t0 = *(const short8*)(tile + r * 72 + c0);
  short8 t1 = *(const short8*)(tile + r * 72 + c0 + 8);
  short* tdst = xT + ((size_t)b * D_ + d0 + r) * L_ + l0 + c0;
  *(short8*)(tdst)     = t0;
  *(short8*)(tdst + 8) = t1;
  float spart = 0.f;
#pragma unroll
  for (int i = 0; i < 8; ++i) spart += bf2f(t0[i]) + bf2f(t1[i]);
  spart += __shfl_xor(spart, 1);
  spart += __shfl_xor(spart, 2);
  if (q == 0) atomicAdd(&s[b * D_ + d0 + r], spart);
}

// ---------------------------------------------------------------------------
// kT: t[b][v] = dot(Lw[v,:], s[b,:]); v >= V_ -> 0
// ---------------------------------------------------------------------------
__global__ __launch_bounds__(256) void kT(const float* __restrict__ Lw,
                                          const float* __restrict__ s,
                                          float* __restrict__ t) {
  const int w = threadIdx.x >> 6, lane = threadIdx.x & 63;
  const int wid = blockIdx.x * 4 + w;
  const int b = wid >> 10, v = wid & 1023;
  float sum = 0.f;
  if (v < V_) {
    const float* lr = Lw + (size_t)v * D_;
    const float* sb = s + b * D_;
#pragma unroll
    for (int i = 0; i < 8; ++i) sum += lr[lane + i * 64] * sb[lane + i * 64];
  }
  for (int off = 32; off; off >>= 1) sum += __shfl_down(sum, off);
  if (lane == 0) t[b * VP + v] = (v < V_) ? sum : 0.f;
}

// ---------------------------------------------------------------------------
// kGbf: Gpart[z] = xT_b[:,chunk] . xT_b[:,chunk]^T  (bf16 out, 128x128 tiles)
// ---------------------------------------------------------------------------
__global__ __launch_bounds__(256) void kGbf(const short* __restrict__ xT,
                                            short* __restrict__ Gpart) {
  const int z = blockIdx.z;
  const int b = z >> 3, ch = z & 7;
  const int i0 = blockIdx.x * 128, j0 = blockIdx.y * 128;
  const short* Ab = xT + (size_t)b * D_ * L_;
  __shared__ short As[128 * 64];
  __shared__ short Bs[128 * 64];
  f32x4 acc[4][4] = {};
  const int tid = threadIdx.x;
  const int w = tid >> 6, lane = tid & 63;
  const int quad = lane >> 4, mcol = lane & 15;
  const int wr0 = (w & 1) * 64, wc0 = (w >> 1) * 64;
  const int kbase = ch * 512;

  for (int k0 = kbase; k0 < kbase + 512; k0 += 64) {
#pragma unroll
    for (int q = 0; q < 4; ++q) {
      const int u = q * 256 + tid;
      const int row = u >> 3, blk = u & 7;
      const int phys = blk ^ (row & 7);
      *(short8*)(As + row * 64 + phys * 8) =
          *(const short8*)(Ab + (size_t)(i0 + row) * L_ + k0 + blk * 8);
      *(short8*)(Bs + row * 64 + phys * 8) =
          *(const short8*)(Ab + (size_t)(j0 + row) * L_ + k0 + blk * 8);
    }
    __syncthreads();
#pragma unroll
    for (int ss = 0; ss < 2; ++ss) {
      short8 af[4], bf[4];
#pragma unroll
      for (int i = 0; i < 4; ++i) {
        const int arow = wr0 + i * 16 + mcol;
        const int ablk = (ss * 4 + quad) ^ (arow & 7);
        af[i] = *(const short8*)(As + arow * 64 + ablk * 8);
        const int brow = wc0 + i * 16 + mcol;
        const int bblk = (ss * 4 + quad) ^ (brow & 7);
        bf[i] = *(const short8*)(Bs + brow * 64 + bblk * 8);
      }
#pragma unroll
      for (int i = 0; i < 4; ++i)
#pragma unroll
        for (int j = 0; j < 4; ++j)
          acc[i][j] = __builtin_amdgcn_mfma_f32_16x16x32_bf16(af[i], bf[j],
                                                              acc[i][j], 0, 0, 0);
    }
    __syncthreads();
  }
  short* Gp = Gpart + (size_t)z * (D_ * D_);
#pragma unroll
  for (int i = 0; i < 4; ++i)
#pragma unroll
    for (int j = 0; j < 4; ++j) {
      const int col = j0 + wc0 + j * 16 + mcol;
#pragma unroll
      for (int r = 0; r < 4; ++r) {
        const int rowi = i0 + wr0 + i * 16 + quad * 4 + r;
        Gp[(size_t)rowi * D_ + col] = f2bf(acc[i][j][r]);
      }
    }
}

// ---------------------------------------------------------------------------
// kGredW: blocks [0,512): Gb = sum_ch Gpart.  blocks [512,1280): cast
// Ww->Wwb, Lw->Lwb (independent work folded in to save a launch).
// ---------------------------------------------------------------------------
__global__ __launch_bounds__(256) void kGredW(const short* __restrict__ Gpart,
                                              short* __restrict__ Gb,
                                              const float* __restrict__ Ww,
                                              const float* __restrict__ Lw,
                                              short* __restrict__ Wwb,
                                              short* __restrict__ Lwb) {
  if (blockIdx.x < 512) {
    const int idx = blockIdx.x * 256 + threadIdx.x;  // short8 index
    const int b = idx >> 15, e = (idx & 32767) * 8;
    float sum[8] = {};
#pragma unroll
    for (int ch = 0; ch < NCH; ++ch) {
      short8 v = *(const short8*)(Gpart + ((size_t)(b * NCH + ch)) * (D_ * D_) + e);
#pragma unroll
      for (int i = 0; i < 8; ++i) sum[i] += bf2f(v[i]);
    }
    short8 o;
#pragma unroll
    for (int i = 0; i < 8; ++i) o[i] = f2bf(sum[i]);
    *(short8*)(Gb + (size_t)b * (D_ * D_) + e) = o;
  } else {
    const int idx = (blockIdx.x - 512) * 256 + threadIdx.x;  // quad index
    if (idx < 65536) {
      const int e = idx * 4;
      float4 f = *(const float4*)(Ww + e);
      short4v o; o[0] = f2bf(f.x); o[1] = f2bf(f.y); o[2] = f2bf(f.z); o[3] = f2bf(f.w);
      *(short4v*)(Wwb + e) = o;
    } else {
      const int e = (idx - 65536) * 4;
      const int v = e >> 9;
      short4v o = {};
      if (v < V_) {
        float4 f = *(const float4*)(Lw + e);
        o[0] = f2bf(f.x); o[1] = f2bf(f.y); o[2] = f2bf(f.z); o[3] = f2bf(f.w);
      }
      *(short4v*)(Lwb + e) = o;
    }
  }
}

// ---------------------------------------------------------------------------
// kMbf64: Mb[b] = Wwb @ Gb[b]  (64x64 tiles, 256 blocks for latency hiding)
// ---------------------------------------------------------------------------
__global__ __launch_bounds__(256) void kMbf64(const short* __restrict__ Wwb,
                                              const short* __restrict__ Gb,
                                              short* __restrict__ Mb) {
  const int b = blockIdx.z;
  const int i0 = blockIdx.x * 64, j0 = blockIdx.y * 64;
  const short* Bbase = Gb + (size_t)b * D_ * D_;
  __shared__ short As[64 * 64];
  __shared__ short Bs[64 * 64];
  f32x4 acc[2][2] = {};
  const int tid = threadIdx.x;
  const int w = tid >> 6, lane = tid & 63;
  const int quad = lane >> 4, mcol = lane & 15;
  const int wr0 = (w & 1) * 32, wc0 = (w >> 1) * 32;

  for (int k0 = 0; k0 < D_; k0 += 64) {
#pragma unroll
    for (int q = 0; q < 2; ++q) {
      const int u = q * 256 + tid;
      const int row = u >> 3, blk = u & 7;
      const int phys = blk ^ (row & 7);
      *(short8*)(As + row * 64 + phys * 8) =
          *(const short8*)(Wwb + (size_t)(i0 + row) * D_ + k0 + blk * 8);
      *(short8*)(Bs + row * 64 + phys * 8) =
          *(const short8*)(Bbase + (size_t)(j0 + row) * D_ + k0 + blk * 8);
    }
    __syncthreads();
#pragma unroll
    for (int ss = 0; ss < 2; ++ss) {
      short8 af[2], bf[2];
#pragma unroll
      for (int i = 0; i < 2; ++i) {
        const int arow = wr0 + i * 16 + mcol;
        const int ablk = (ss * 4 + quad) ^ (arow & 7);
        af[i] = *(const short8*)(As + arow * 64 + ablk * 8);
        const int brow = wc0 + i * 16 + mcol;
        const int bblk = (ss * 4 + quad) ^ (brow & 7);
        bf[i] = *(const short8*)(Bs + brow * 64 + bblk * 8);
      }
#pragma unroll
      for (int i = 0; i < 2; ++i)
#pragma unroll
        for (int j = 0; j < 2; ++j)
          acc[i][j] = __builtin_amdgcn_mfma_f32_16x16x32_bf16(af[i], bf[j],
                                                              acc[i][j], 0, 0, 0);
    }
    __syncthreads();
  }
  short* Mo = Mb + (size_t)b * D_ * D_;
#pragma unroll
  for (int i = 0; i < 2; ++i)
#pragma unroll
    for (int j = 0; j < 2; ++j) {
      const int col = j0 + wc0 + j * 16 + mcol;
#pragma unroll
      for (int r = 0; r < 4; ++r) {
        const int rowi = i0 + wr0 + i * 16 + quad * 4 + r;
        Mo[(size_t)rowi * D_ + col] = f2bf(acc[i][j][r]);
      }
    }
}

// ---------------------------------------------------------------------------
// kPbf64: Ptb[b][v][d] = sum_j Lwb[v,j] * Mb[b][d,j]  (64x64 tiles)
// ---------------------------------------------------------------------------
__global__ __launch_bounds__(256) void kPbf64(const short* __restrict__ Lwb,
                                              const short* __restrict__ Mb,
                                              short* __restrict__ Ptb) {
  const int b = blockIdx.z;
  const int i0 = blockIdx.x * 64;  // v
  const int j0 = blockIdx.y * 64;  // d
  const short* Bbase = Mb + (size_t)b * D_ * D_;
  __shared__ short As[64 * 64];
  __shared__ short Bs[64 * 64];
  f32x4 acc[2][2] = {};
  const int tid = threadIdx.x;
  const int w = tid >> 6, lane = tid & 63;
  const int quad = lane >> 4, mcol = lane & 15;
  const int wr0 = (w & 1) * 32, wc0 = (w >> 1) * 32;

  for (int k0 = 0; k0 < D_; k0 += 64) {
#pragma unroll
    for (int q = 0; q < 2; ++q) {
      const int u = q * 256 + tid;
      const int row = u >> 3, blk = u & 7;
      const int phys = blk ^ (row & 7);
      *(short8*)(As + row * 64 + phys * 8) =
          *(const short8*)(Lwb + (size_t)(i0 + row) * D_ + k0 + blk * 8);
      *(short8*)(Bs + row * 64 + phys * 8) =
          *(const short8*)(Bbase + (size_t)(j0 + row) * D_ + k0 + blk * 8);
    }
    __syncthreads();
#pragma unroll
    for (int ss = 0; ss < 2; ++ss) {
      short8 af[2], bf[2];
#pragma unroll
      for (int i = 0; i < 2; ++i) {
        const int arow = wr0 + i * 16 + mcol;
        const int ablk = (ss * 4 + quad) ^ (arow & 7);
        af[i] = *(const short8*)(As + arow * 64 + ablk * 8);
        const int brow = wc0 + i * 16 + mcol;
        const int bblk = (ss * 4 + quad) ^ (brow & 7);
        bf[i] = *(const short8*)(Bs + brow * 64 + bblk * 8);
      }
#pragma unroll
      for (int i = 0; i < 2; ++i)
#pragma unroll
        for (int j = 0; j < 2; ++j)
          acc[i][j] = __builtin_amdgcn_mfma_f32_16x16x32_bf16(af[i], bf[j],
                                                              acc[i][j], 0, 0, 0);
    }
    __syncthreads();
  }
  short* Po = Ptb + (size_t)b * VP * D_;
#pragma unroll
  for (int i = 0; i < 2; ++i)
#pragma unroll
    for (int j = 0; j < 2; ++j) {
      const int col = j0 + wc0 + j * 16 + mcol;
#pragma unroll
      for (int r = 0; r < 4; ++r) {
        const int rowi = i0 + wr0 + i * 16 + quad * 4 + r;
        Po[(size_t)rowi * D_ + col] = f2bf(acc[i][j][r]);
      }
    }
}

// ---------------------------------------------------------------------------
// kLogits2: logits[b,l,v] = x[l]·Ptb[v] + c[b,l]*t[b,v] + Lb[v], bf16 out.
// A = Ptb (v-rows), B = xbf (l-rows) -> lane holds 4 consecutive v at one l.
// GRID: x = l-tile (fastest) so XCD assignment is stable across the v-sweep
// (per-XCD L2 reuse of xbf; round-3-validated pattern, FETCH ~25 MB).
// ---------------------------------------------------------------------------
__global__ __launch_bounds__(256) void kLogits2(const short* __restrict__ xbf,
                                                const short* __restrict__ Ptb,
                                                const float* __restrict__ c,
                                                const float* __restrict__ t,
                                                const float* __restrict__ Lb,
                                                short* __restrict__ logitsBf) {
  const int b = blockIdx.z;
  const int l0t = blockIdx.x * 128;  // l tile (fastest-varying)
  const int v0t = blockIdx.y * 128;  // v tile
  const short* Abase = Ptb + (size_t)b * VP * D_;
  const short* Bbase = xbf + (size_t)b * L_ * D_;
  __shared__ short As[128 * 64];
  __shared__ short Bs[128 * 64];
  f32x4 acc[4][4] = {};
  const int tid = threadIdx.x;
  const int w = tid >> 6, lane = tid & 63;
  const int quad = lane >> 4, mcol = lane & 15;
  const int wr0 = (w & 1) * 64, wc0 = (w >> 1) * 64;

  for (int k0 = 0; k0 < D_; k0 += 64) {
#pragma unroll
    for (int q = 0; q < 4; ++q) {
      const int u = q * 256 + tid;
      const int row = u >> 3, blk = u & 7;
      const int phys = blk ^ (row & 7);
      *(short8*)(As + row * 64 + phys * 8) =
          *(const short8*)(Abase + (size_t)(v0t + row) * D_ + k0 + blk * 8);
      *(short8*)(Bs + row * 64 + phys * 8) =
          *(const short8*)(Bbase + (size_t)(l0t + row) * D_ + k0 + blk * 8);
    }
    __syncthreads();
#pragma unroll
    for (int ss = 0; ss < 2; ++ss) {
      short8 af[4], bf[4];
#pragma unroll
      for (int i = 0; i < 4; ++i) {
        const int arow = wr0 + i * 16 + mcol;
        const int ablk = (ss * 4 + quad) ^ (arow & 7);
        af[i] = *(const short8*)(As + arow * 64 + ablk * 8);
        const int brow = wc0 + i * 16 + mcol;
        const int bblk = (ss * 4 + quad) ^ (brow & 7);
        bf[i] = *(const short8*)(Bs + brow * 64 + bblk * 8);
      }
#pragma unroll
      for (int i = 0; i < 4; ++i)
#pragma unroll
        for (int j = 0; j < 4; ++j)
          acc[i][j] = __builtin_amdgcn_mfma_f32_16x16x32_bf16(af[i], bf[j],
                                                              acc[i][j], 0, 0, 0);
    }
    __syncthreads();
  }
  // C[row=v][col=l]: v = v0t+wr0+i*16+quad*4+r (consecutive in r), l = wc0+j*16+mcol
#pragma unroll
  for (int j = 0; j < 4; ++j) {
    const int gl = l0t + wc0 + j * 16 + mcol;
    const float cl = c[b * L_ + gl];
#pragma unroll
    for (int i = 0; i < 4; ++i) {
      const int gv0 = v0t + wr0 + i * 16 + quad * 4;
      f32x4 tv = *(const f32x4*)(t + b * VP + gv0);
      f32x4 lb4 = {};
      if (gv0 < V_) lb4 = *(const f32x4*)(Lb + gv0);  // V_ % 4 == 0
      short4v o;
#pragma unroll
      for (int r = 0; r < 4; ++r)
        o[r] = f2bf(acc[i][j][r] + cl * tv[r] + lb4[r]);
      *(short4v*)(logitsBf + ((size_t)b * L_ + gl) * VP + gv0) = o;
    }
  }
}

// ---------------------------------------------------------------------------
// kLsm: log_softmax over V per (b,l) row, bf16 logits in, fp32 out (L,B,V).
// One wave per row; no LDS, no barriers.
// ---------------------------------------------------------------------------
__global__ __launch_bounds__(256) void kLsm(const short* __restrict__ logitsBf,
                                            float* __restrict__ out) {
  const int b = blockIdx.y;
  const int l = blockIdx.x * 4 + (threadIdx.x >> 6);
  const int lane = threadIdx.x & 63;
  const short* row = logitsBf + ((size_t)b * L_ + l) * VP;
  short8 v0 = *(const short8*)(row + lane * 16);
  short8 v1 = *(const short8*)(row + lane * 16 + 8);
  float vals[16];
#pragma unroll
  for (int i = 0; i < 8; ++i) { vals[i] = bf2f(v0[i]); vals[8 + i] = bf2f(v1[i]); }
  float m = -__builtin_inff();
#pragma unroll
  for (int i = 0; i < 16; ++i)
    if (lane * 16 + i < V_) m = fmaxf(m, vals[i]);
  for (int off = 32; off; off >>= 1) m = fmaxf(m, __shfl_xor(m, off));
  float se = 0.f;
#pragma unroll
  for (int i = 0; i < 16; ++i)
    if (lane * 16 + i < V_) se += expf(vals[i] - m);
  for (int off = 32; off; off >>= 1) se += __shfl_xor(se, off);
  const float lse = m + logf(se);
  float* orow = out + (size_t)l * OUT_BV + b * V_;
#pragma unroll
  for (int q = 0; q < 4; ++q) {
    const int base = lane * 16 + q * 4;
    if (base < V_) {  // V_ % 4 == 0, so base<V_ implies base+3<V_
      float4 st = make_float4(vals[q * 4 + 0] - lse, vals[q * 4 + 1] - lse,
                              vals[q * 4 + 2] - lse, vals[q * 4 + 3] - lse);
      *(float4*)(orow + base) = st;
    }
  }
}

// ---------------------------------------------------------------------------
extern "C" void kernel_launch(void* const* d_in, const int* in_sizes, int n_in,
                              void* d_out, int out_size, void* d_ws,
                              size_t ws_size, hipStream_t stream) {
  const float* x  = (const float*)d_in[0];
  const float* Ww = (const float*)d_in[1];
  const float* Wb = (const float*)d_in[2];
  const float* Lw = (const float*)d_in[3];
  const float* Lb = (const float*)d_in[4];

  char* wp = (char*)d_ws;
  short* xbf = (short*)wp;   wp += (size_t)B_ * L_ * D_ * 2;        // 16 MB
  short* xT  = (short*)wp;   wp += (size_t)B_ * L_ * D_ * 2;        // 16 MB
  short* Ptb = (short*)wp;   wp += (size_t)B_ * VP * D_ * 2;        // 4 MB
  short* Gpart = (short*)wp; wp += (size_t)B_ * NCH * D_ * D_ * 2;  // 16 MB
  short* Gb  = (short*)wp;   wp += (size_t)B_ * D_ * D_ * 2;        // 2 MB
  short* Mb  = (short*)wp;   wp += (size_t)B_ * D_ * D_ * 2;        // 2 MB
  short* Wwb = (short*)wp;   wp += (size_t)D_ * D_ * 2;             // 0.5 MB
  short* Lwb = (short*)wp;   wp += (size_t)VP * D_ * 2;             // 1 MB
  float* s   = (float*)wp;   wp += (size_t)B_ * D_ * 4;             // 8 KB
  float* c   = (float*)wp;   wp += (size_t)B_ * L_ * 4;             // 64 KB
  float* t   = (float*)wp;   wp += (size_t)B_ * VP * 4;             // 16 KB
  short* logitsBf = (short*)wp;                                     // 32 MB

  // zero the atomic accumulators (s and c are contiguous)
  hipMemsetAsync(s, 0, (size_t)(B_ * D_ + B_ * L_) * sizeof(float), stream);

  kPre<<<dim3(64, 8, B_), 256, 0, stream>>>(x, Wb, xbf, xT, s, c);
  kGbf<<<dim3(4, 4, B_ * NCH), 256, 0, stream>>>(xT, Gpart);
  kGredW<<<dim3(1280), 256, 0, stream>>>(Gpart, Gb, Ww, Lw, Wwb, Lwb);
  kMbf64<<<dim3(8, 8, B_), 256, 0, stream>>>(Wwb, Gb, Mb);
  kT<<<dim3(1024), 256, 0, stream>>>(Lw, s, t);
  kPbf64<<<dim3(16, 8, B_), 256, 0, stream>>>(Lwb, Mb, Ptb);
  kLogits2<<<dim3(32, 8, B_), 256, 0, stream>>>(xbf, Ptb, c, t, Lb, logitsBf);
  kLsm<<<dim3(L_ / 4, B_), 256, 0, stream>>>(logitsBf, (float*)d_out);
}